// Round 6
// baseline (128.381 us; speedup 1.0000x reference)
//
#include <hip/hip_runtime.h>

typedef unsigned short u16;
typedef unsigned int u32;
typedef __attribute__((ext_vector_type(4))) unsigned short u16x4;
typedef __attribute__((ext_vector_type(8))) unsigned short u16x8;
typedef __attribute__((ext_vector_type(8))) __bf16 bf16x8;
typedef __attribute__((ext_vector_type(4))) float f32x4;
typedef __attribute__((ext_vector_type(16))) float f32x16;

#define SEQ 2048
#define DMODEL 1024
#define LDP 3072
#define MM (DMODEL * DMODEL)
#define SC 0.18033688f  // (1/8) * log2(e)

__device__ __forceinline__ u16 f2bf(float f) {
  unsigned u = __builtin_bit_cast(unsigned, f);
  u = (u + 0x7fffu + ((u >> 16) & 1u)) >> 16;
  return (u16)u;
}

__device__ __forceinline__ u32 cvtpk(float lo, float hi) {
  u32 r;
  asm volatile("v_cvt_pk_bf16_f32 %0, %1, %2" : "=v"(r) : "v"(lo), "v"(hi));
  return r;
}

__device__ __forceinline__ float fexp2(float x) {
#if __has_builtin(__builtin_amdgcn_exp2f)
  return __builtin_amdgcn_exp2f(x);
#else
  return exp2f(x);
#endif
}

__device__ __forceinline__ bf16x8 ldbf8(const u16* p) {
  return __builtin_bit_cast(bf16x8, *(const u16x8*)p);
}
__device__ __forceinline__ bf16x8 ldbf8c(const char* p) {
  return __builtin_bit_cast(bf16x8, *(const u16x8*)p);
}

__device__ __forceinline__ f32x4 mfma16(bf16x8 a, bf16x8 b, f32x4 c) {
  return __builtin_amdgcn_mfma_f32_16x16x32_bf16(a, b, c, 0, 0, 0);
}
__device__ __forceinline__ f32x16 mfma32(bf16x8 a, bf16x8 b, f32x16 c) {
  return __builtin_amdgcn_mfma_f32_32x32x16_bf16(a, b, c, 0, 0, 0);
}

__device__ __forceinline__ void gl16(const void* g, void* l) {
  __builtin_amdgcn_global_load_lds(
      (__attribute__((address_space(1))) void*)(size_t)g,
      (__attribute__((address_space(3))) void*)l, 16, 0, 0);
}

// ----------------- fp32 -> bf16 cast (single merged kernel) -----------------
__global__ void cast_all_k(const float* __restrict__ q, const float* __restrict__ k,
                           const float* __restrict__ v, const float* __restrict__ wq,
                           const float* __restrict__ wk, const float* __restrict__ wv,
                           const float* __restrict__ wo, u16* __restrict__ dq,
                           u16* __restrict__ dk, u16* __restrict__ dv,
                           u16* __restrict__ wqkv, u16* __restrict__ wob) {
  int b = blockIdx.x;
  const float* s;
  u16* d;
  if (b < 6144) {  // q,k,v: 2048 blocks each
    const int z = b >> 11;
    s = z == 0 ? q : z == 1 ? k : v;
    d = z == 0 ? dq : z == 1 ? dk : dv;
    b &= 2047;
  } else {  // weights: 512 blocks each
    const int z = (b - 6144) >> 9;
    s = z == 0 ? wq : z == 1 ? wk : z == 2 ? wv : wo;
    d = z < 3 ? wqkv + (size_t)z * MM : wob;
    b = (b - 6144) & 511;
  }
  const size_t i = ((size_t)b * blockDim.x + threadIdx.x) * 8;
  const float4 a = *(const float4*)(s + i);
  const float4 c = *(const float4*)(s + i + 4);
  u16x8 o;
  o[0] = f2bf(a.x); o[1] = f2bf(a.y); o[2] = f2bf(a.z); o[3] = f2bf(a.w);
  o[4] = f2bf(c.x); o[5] = f2bf(c.y); o[6] = f2bf(c.z); o[7] = f2bf(c.w);
  *(u16x8*)(d + i) = o;
}

// ----------------- GEMM: C = A @ B^T + bias (m97 structure) -----------------
template <int OMODE>
__device__ __forceinline__ void gemm_bt_body(const u16* __restrict__ A,
                                             const u16* __restrict__ Bw,
                                             const float* __restrict__ bias,
                                             void* __restrict__ Cv, const int K,
                                             const int ldc, const int ncol0,
                                             const int m0, const int n0) {
  __shared__ u16 As[128 * 32];
  __shared__ u16 Bs[128 * 32];
  const int tid = threadIdx.x;
  const int lane = tid & 63;
  const int w = tid >> 6;
  const int l15 = lane & 15;
  const int lg = lane >> 4;

  f32x4 acc[4][4] = {};

  const int arow = (w >> 1) * 64 + l15;
  const int brow = (w & 1) * 64 + l15;
  const int kfb = lg * 16;

  const int strow = w * 32 + (lane >> 2);
  const u16* Ag = A + (size_t)(m0 + strow) * K + (lane & 3) * 8;
  const u16* Bg = Bw + (size_t)(n0 + strow) * K + (lane & 3) * 8;
  const size_t rstep = (size_t)16 * K;
  char* AsL0 = (char*)As + w * 32 * 64;
  char* AsL1 = AsL0 + 16 * 64;
  char* BsL0 = (char*)Bs + w * 32 * 64;
  char* BsL1 = BsL0 + 16 * 64;

  for (int k0 = 0; k0 < K; k0 += 32) {
    __syncthreads();
    gl16(Ag + k0, AsL0);
    gl16(Ag + k0 + rstep, AsL1);
    gl16(Bg + k0, BsL0);
    gl16(Bg + k0 + rstep, BsL1);
    __syncthreads();
    bf16x8 af[4], bfv[4];
#pragma unroll
    for (int t = 0; t < 4; ++t) {
      af[t] = ldbf8c((char*)As + (arow + t * 16) * 64 + kfb);
      bfv[t] = ldbf8c((char*)Bs + (brow + t * 16) * 64 + kfb);
    }
    __builtin_amdgcn_s_setprio(1);
#pragma unroll
    for (int i = 0; i < 4; ++i)
#pragma unroll
      for (int j = 0; j < 4; ++j) acc[i][j] = mfma16(af[i], bfv[j], acc[i][j]);
    __builtin_amdgcn_s_setprio(0);
  }

  const int mrow = (w >> 1) * 64 + lg * 4;
  const int ncol = (w & 1) * 64 + l15;
#pragma unroll
  for (int j = 0; j < 4; ++j) {
    const int gn = n0 + ncol + j * 16;
    const float bia = bias[gn];
#pragma unroll
    for (int i = 0; i < 4; ++i) {
      const int gmb = m0 + mrow + i * 16;
#pragma unroll
      for (int r = 0; r < 4; ++r) {
        const float val = acc[i][j][r] + bia;
        const int gm = gmb + r;
        if (OMODE == 0) {
          ((float*)Cv)[(size_t)gm * ldc + gn] = val;
        } else if (OMODE == 1) {
          ((u16*)Cv)[(size_t)gm * ldc + ncol0 + gn] = f2bf(val);
        } else {
          const int bb = gm >> 11, ss = gm & 2047;
          const int hh = gn >> 6, dd = gn & 63;
          ((u16*)Cv)[(((size_t)(bb * 16 + hh) * 64 + dd) << 11) + ss] = f2bf(val);
        }
      }
    }
  }
}

// XCD-chunked QKV projections (768 blocks; xcd = b&7).
__global__ __launch_bounds__(256, 3) void gemm_qkv_k(
    const u16* __restrict__ qb, const u16* __restrict__ kb,
    const u16* __restrict__ vb, const u16* __restrict__ wqkv,
    const float* __restrict__ bq, const float* __restrict__ bk,
    const float* __restrict__ bv, u16* __restrict__ proj, u16* __restrict__ vtb) {
  const int b = blockIdx.x;
  const int xcd = b & 7;
  const int i = b >> 3;
  const int z = i >> 5;
  const int j = i & 31;
  const int m0 = (xcd * 4 + (j >> 3)) * 128;
  const int n0 = (j & 7) * 128;
  if (z == 2)
    gemm_bt_body<2>(vb, wqkv + 2 * (size_t)MM, bv, vtb, DMODEL, 0, 0, m0, n0);
  else
    gemm_bt_body<1>(z == 0 ? qb : kb, wqkv + (size_t)z * MM, z == 0 ? bq : bk,
                    proj, DMODEL, LDP, z * DMODEL, m0, n0);
}

__global__ __launch_bounds__(256, 3) void gemm_o_k(const u16* __restrict__ attnb,
                                                   const u16* __restrict__ wob,
                                                   const float* __restrict__ bo,
                                                   float* __restrict__ out) {
  const int b = blockIdx.x;
  const int xcd = b & 7;
  const int i = b >> 3;
  const int m0 = (xcd * 4 + (i >> 3)) * 128;
  const int n0 = (i & 7) * 128;
  gemm_bt_body<0>(attnb, wob, bo, out, DMODEL, DMODEL, 0, m0, n0);
}

// ----------------- flash attention: 32x32 MFMA, 2-tile pipelined -----------
// 512 blocks (2/CU); xcd = b&7, 4 heads/XCD. Block = 128 q rows; 4 waves,
// wave w owns q = qB + w*32 + l31. hi = lane>>5.
// Per big-iter: tiles A (ks[0]/vs[0]) and B (ks[1]/vs[1]) computed in one
// barrier-free region (QKT_B MFMAs overlap SM_A VALU chain); 2 barriers per
// 2 tiles. K swizzle (row&7)<<4 (b128); V swizzle (row&15)<<3 (b64-aligned,
// conflict-free 16-lane phases on both write and read).
__global__ __launch_bounds__(256, 2) void attn_k(const u16* __restrict__ proj,
                                                 const u16* __restrict__ vtb,
                                                 u16* __restrict__ outa) {
  __shared__ u16 ks[2][64 * 64];
  __shared__ u16 vs[2][64 * 64];
  const int b = blockIdx.x;
  const int slot = b >> 3;
  const int bh = (b & 7) * 4 + (slot >> 4);
  const int qB = (slot & 15) * 128;
  const int tid = threadIdx.x;
  const int lane = tid & 63;
  const int w = tid >> 6;
  const size_t rb = (size_t)(bh >> 4) * SEQ;
  const int h = bh & 15;
  const int l31 = lane & 31;
  const int hi = lane >> 5;
  const int swzk = (l31 & 7) << 4;
  const int swzv = (l31 & 15) << 3;

  // Q B-frags: Q[q][d = km*16 + hi*8 + j]
  const u16* qp = proj + (rb + qB + w * 32 + l31) * LDP + h * 64 + hi * 8;
  bf16x8 qf[4];
#pragma unroll
  for (int km = 0; km < 4; ++km) qf[km] = ldbf8(qp + km * 16);

  // staging: row = tid>>2 (64 rows), byte col (tid&3)*32
  const int srow = tid >> 2;
  const int scol = (tid & 3) * 32;
  const int scel = scol >> 1;
  const int kz0 = srow * 128 + (scol ^ ((srow & 7) << 4));
  const int kz1 = srow * 128 + ((scol + 16) ^ ((srow & 7) << 4));
  const int vz0 = srow * 128 + (scol ^ ((srow & 15) << 3));
  const int vz1 = srow * 128 + ((scol + 8) ^ ((srow & 15) << 3));
  const int vz2 = srow * 128 + ((scol + 16) ^ ((srow & 15) << 3));
  const int vz3 = srow * 128 + ((scol + 24) ^ ((srow & 15) << 3));
  const u16* kg = proj + rb * LDP + DMODEL + h * 64;  // K rows, stride LDP
  const u16* vg = vtb + (size_t)bh * 64 * SEQ;        // V^T rows [d][s]

  u16x8 kA0, kA1, kB0, kB1, vA0, vA1, vB0, vB1;

#define LOADPAIR(KV)                                                     \
  {                                                                      \
    const u16* krA = kg + (size_t)((KV) + srow) * LDP + scel;            \
    kA0 = *(const u16x8*)krA;                                            \
    kA1 = *(const u16x8*)(krA + 8);                                      \
    const u16* krB = kg + (size_t)((KV) + 64 + srow) * LDP + scel;       \
    kB0 = *(const u16x8*)krB;                                            \
    kB1 = *(const u16x8*)(krB + 8);                                      \
    const u16* vrA = vg + (size_t)srow * SEQ + (KV) + scel;              \
    vA0 = *(const u16x8*)vrA;                                            \
    vA1 = *(const u16x8*)(vrA + 8);                                      \
    vB0 = *(const u16x8*)(vrA + 64);                                     \
    vB1 = *(const u16x8*)(vrA + 72);                                     \
  }

#define WRITEPAIR()                                                      \
  {                                                                      \
    char* k0d = (char*)ks[0];                                            \
    char* k1d = (char*)ks[1];                                            \
    char* v0d = (char*)vs[0];                                            \
    char* v1d = (char*)vs[1];                                            \
    *(u16x8*)(k0d + kz0) = kA0;                                          \
    *(u16x8*)(k0d + kz1) = kA1;                                          \
    *(u16x8*)(k1d + kz0) = kB0;                                          \
    *(u16x8*)(k1d + kz1) = kB1;                                          \
    *(u16x4*)(v0d + vz0) = *(u16x4*)&vA0;                                \
    *(u16x4*)(v0d + vz1) = *((u16x4*)&vA0 + 1);                          \
    *(u16x4*)(v0d + vz2) = *(u16x4*)&vA1;                                \
    *(u16x4*)(v0d + vz3) = *((u16x4*)&vA1 + 1);                          \
    *(u16x4*)(v1d + vz0) = *(u16x4*)&vB0;                                \
    *(u16x4*)(v1d + vz1) = *((u16x4*)&vB0 + 1);                          \
    *(u16x4*)(v1d + vz2) = *(u16x4*)&vB1;                                \
    *(u16x4*)(v1d + vz3) = *((u16x4*)&vB1 + 1);                          \
  }

#define QKT(S0, S1, KP)                                                  \
  {                                                                      \
    __builtin_amdgcn_s_setprio(1);                                       \
    _Pragma("unroll") for (int km = 0; km < 4; ++km) {                   \
      const int co = (km * 32 + hi * 16) ^ swzk;                         \
      const bf16x8 k0 = ldbf8c((KP) + l31 * 128 + co);                   \
      const bf16x8 k1 = ldbf8c((KP) + (32 + l31) * 128 + co);            \
      S0 = mfma32(k0, qf[km], S0);                                       \
      S1 = mfma32(k1, qf[km], S1);                                       \
    }                                                                    \
    __builtin_amdgcn_s_setprio(0);                                       \
  }

#define PCHUNK(SV, G, CB, VP)                                            \
  {                                                                      \
    u16x8 pbu;                                                           \
    ((u32*)&pbu)[0] = cvtpk(SV[G + 0], SV[G + 1]);                       \
    ((u32*)&pbu)[1] = cvtpk(SV[G + 2], SV[G + 3]);                       \
    ((u32*)&pbu)[2] = cvtpk(SV[G + 4], SV[G + 5]);                       \
    ((u32*)&pbu)[3] = cvtpk(SV[G + 6], SV[G + 7]);                       \
    const bf16x8 pb = __builtin_bit_cast(bf16x8, pbu);                   \
    const int vc0 = ((CB) + 8 * hi) ^ swzv;                              \
    const int vc1 = ((CB) + 16 + 8 * hi) ^ swzv;                         \
    const char* vr0 = (VP) + l31 * 128;                                  \
    const char* vr1 = (VP) + (32 + l31) * 128;                           \
    u16x8 vf0, vf1;                                                      \
    *(u16x4*)&vf0 = *(const u16x4*)(vr0 + vc0);                          \
    *((u16x4*)&vf0 + 1) = *(const u16x4*)(vr0 + vc1);                    \
    *(u16x4*)&vf1 = *(const u16x4*)(vr1 + vc0);                          \
    *((u16x4*)&vf1 + 1) = *(const u16x4*)(vr1 + vc1);                    \
    oa0 = mfma32(__builtin_bit_cast(bf16x8, vf0), pb, oa0);              \
    oa1 = mfma32(__builtin_bit_cast(bf16x8, vf1), pb, oa1);              \
  }

#define SOFTPV(S0, S1, VP)                                               \
  {                                                                      \
    float mxq0 = fmaxf(fmaxf(S0[0], S0[1]), fmaxf(S0[2], S0[3]));        \
    float mxq1 = fmaxf(fmaxf(S0[4], S0[5]), fmaxf(S0[6], S0[7]));        \
    float mxq2 = fmaxf(fmaxf(S0[8], S0[9]), fmaxf(S0[10], S0[11]));      \
    float mxq3 = fmaxf(fmaxf(S0[12], S0[13]), fmaxf(S0[14], S0[15]));    \
    float mxq4 = fmaxf(fmaxf(S1[0], S1[1]), fmaxf(S1[2], S1[3]));        \
    float mxq5 = fmaxf(fmaxf(S1[4], S1[5]), fmaxf(S1[6], S1[7]));        \
    float mxq6 = fmaxf(fmaxf(S1[8], S1[9]), fmaxf(S1[10], S1[11]));      \
    float mxq7 = fmaxf(fmaxf(S1[12], S1[13]), fmaxf(S1[14], S1[15]));    \
    float mx = fmaxf(fmaxf(fmaxf(mxq0, mxq1), fmaxf(mxq2, mxq3)),        \
                     fmaxf(fmaxf(mxq4, mxq5), fmaxf(mxq6, mxq7)));       \
    mx = fmaxf(mx, __shfl_xor(mx, 32));                                  \
    if (!__all(mx <= mrun + 64.0f)) {                                    \
      const float mn = fmaxf(mrun, mx);                                  \
      const float sf = fexp2((mrun - mn) * SC);                          \
      mrun = mn;                                                         \
      lrun *= sf;                                                        \
      _Pragma("unroll") for (int r = 0; r < 16; ++r) {                   \
        oa0[r] *= sf;                                                    \
        oa1[r] *= sf;                                                    \
      }                                                                  \
    }                                                                    \
    const float nmc = -mrun * SC;                                        \
    _Pragma("unroll") for (int r = 0; r < 16; ++r)                       \
        S0[r] = fexp2(__builtin_fmaf(S0[r], SC, nmc));                   \
    _Pragma("unroll") for (int r = 0; r < 16; ++r)                       \
        S1[r] = fexp2(__builtin_fmaf(S1[r], SC, nmc));                   \
    float rs = (((S0[0] + S0[1]) + (S0[2] + S0[3])) +                    \
                ((S0[4] + S0[5]) + (S0[6] + S0[7]))) +                   \
               (((S0[8] + S0[9]) + (S0[10] + S0[11])) +                  \
                ((S0[12] + S0[13]) + (S0[14] + S0[15])));                \
    rs += (((S1[0] + S1[1]) + (S1[2] + S1[3])) +                         \
           ((S1[4] + S1[5]) + (S1[6] + S1[7]))) +                        \
          (((S1[8] + S1[9]) + (S1[10] + S1[11])) +                       \
           ((S1[12] + S1[13]) + (S1[14] + S1[15])));                     \
    rs += __shfl_xor(rs, 32);                                            \
    lrun += rs;                                                          \
    __builtin_amdgcn_s_setprio(1);                                       \
    PCHUNK(S0, 0, 0, VP)                                                 \
    PCHUNK(S0, 8, 32, VP)                                                \
    PCHUNK(S1, 0, 64, VP)                                                \
    PCHUNK(S1, 8, 96, VP)                                                \
    __builtin_amdgcn_s_setprio(0);                                       \
  }

  f32x16 oa0 = {}, oa1 = {};
  float mrun = -3.0e38f, lrun = 0.f;

  LOADPAIR(0);
  WRITEPAIR();
  __syncthreads();

  for (int it = 0; it < SEQ / 128; ++it) {
    if (it + 1 < SEQ / 128) LOADPAIR((it + 1) * 128);
    f32x16 s0A = {}, s1A = {}, s0B = {}, s1B = {};
    QKT(s0A, s1A, (const char*)ks[0])
    QKT(s0B, s1B, (const char*)ks[1])
    SOFTPV(s0A, s1A, (const char*)vs[0])
    SOFTPV(s0B, s1B, (const char*)vs[1])
    if (it + 1 < SEQ / 128) {
      __syncthreads();  // all reads of both bufs done
      WRITEPAIR();      // compiler waits vmcnt; latency covered by compute
      __syncthreads();  // writes visible
    }
  }
#undef LOADPAIR
#undef WRITEPAIR
#undef QKT
#undef PCHUNK
#undef SOFTPV

  // ---- epilogue: O^T[d][q] -> attnb[q][h*64+d] ----
  const float invl = 1.0f / lrun;
  u16* orow = outa + (rb + qB + w * 32 + l31) * DMODEL + h * 64 + hi * 4;
#pragma unroll
  for (int g = 0; g < 4; ++g) {
    u16x4 st0, st1;
    ((u32*)&st0)[0] = cvtpk(oa0[4 * g + 0] * invl, oa0[4 * g + 1] * invl);
    ((u32*)&st0)[1] = cvtpk(oa0[4 * g + 2] * invl, oa0[4 * g + 3] * invl);
    *(u16x4*)(orow + 8 * g) = st0;
    ((u32*)&st1)[0] = cvtpk(oa1[4 * g + 0] * invl, oa1[4 * g + 1] * invl);
    ((u32*)&st1)[1] = cvtpk(oa1[4 * g + 2] * invl, oa1[4 * g + 3] * invl);
    *(u16x4*)(orow + 32 + 8 * g) = st1;
  }
}

extern "C" void kernel_launch(void* const* d_in, const int* in_sizes, int n_in,
                              void* d_out, int out_size, void* d_ws, size_t ws_size,
                              hipStream_t stream) {
  const float* q  = (const float*)d_in[0];
  const float* k  = (const float*)d_in[1];
  const float* v  = (const float*)d_in[2];
  const float* wq = (const float*)d_in[3];
  const float* bq = (const float*)d_in[4];
  const float* wk = (const float*)d_in[5];
  const float* bk = (const float*)d_in[6];
  const float* wv = (const float*)d_in[7];
  const float* bv = (const float*)d_in[8];
  const float* wo = (const float*)d_in[9];
  const float* bo = (const float*)d_in[10];

  const size_t NTOK = (size_t)2 * SEQ;
  const size_t NELE = NTOK * DMODEL;
  u16* qb    = (u16*)d_ws;
  u16* kb    = qb + NELE;
  u16* vb    = kb + NELE;
  u16* wqkv  = vb + NELE;
  u16* wob   = wqkv + 3 * (size_t)MM;
  u16* projb = wob + (size_t)MM;
  u16* vtb   = projb + NTOK * LDP;
  u16* attnb = qb;  // qb dead after projections -> reuse

  cast_all_k<<<8192, 256, 0, stream>>>(q, k, v, wq, wk, wv, wo, qb, kb, vb,
                                       wqkv, wob);
  gemm_qkv_k<<<768, 256, 0, stream>>>(qb, kb, vb, wqkv, bq, bk, bv, projb, vtb);
  attn_k<<<512, 256, 0, stream>>>(projb, vtb, attnb);
  gemm_o_k<<<256, 256, 0, stream>>>(attnb, wob, bo, (float*)d_out);
}

// Round 7
// 120.119 us; speedup vs baseline: 1.0688x; 1.0688x over previous
//
#include <hip/hip_runtime.h>

typedef unsigned short u16;
typedef unsigned int u32;
typedef __attribute__((ext_vector_type(4))) unsigned short u16x4;
typedef __attribute__((ext_vector_type(8))) unsigned short u16x8;
typedef __attribute__((ext_vector_type(8))) __bf16 bf16x8;
typedef __attribute__((ext_vector_type(4))) float f32x4;
typedef __attribute__((ext_vector_type(16))) float f32x16;

#define SEQ 2048
#define DMODEL 1024
#define LDP 3072
#define MM (DMODEL * DMODEL)
#define SC 0.18033688f  // (1/8) * log2(e)

__device__ __forceinline__ u16 f2bf(float f) {
  unsigned u = __builtin_bit_cast(unsigned, f);
  u = (u + 0x7fffu + ((u >> 16) & 1u)) >> 16;
  return (u16)u;
}

__device__ __forceinline__ u32 cvtpk(float lo, float hi) {
  u32 r;
  asm volatile("v_cvt_pk_bf16_f32 %0, %1, %2" : "=v"(r) : "v"(lo), "v"(hi));
  return r;
}

__device__ __forceinline__ float fexp2(float x) {
#if __has_builtin(__builtin_amdgcn_exp2f)
  return __builtin_amdgcn_exp2f(x);
#else
  return exp2f(x);
#endif
}

__device__ __forceinline__ bf16x8 ldbf8(const u16* p) {
  return __builtin_bit_cast(bf16x8, *(const u16x8*)p);
}
__device__ __forceinline__ bf16x8 ldbf8c(const char* p) {
  return __builtin_bit_cast(bf16x8, *(const u16x8*)p);
}

__device__ __forceinline__ f32x4 mfma16(bf16x8 a, bf16x8 b, f32x4 c) {
  return __builtin_amdgcn_mfma_f32_16x16x32_bf16(a, b, c, 0, 0, 0);
}
__device__ __forceinline__ f32x16 mfma32(bf16x8 a, bf16x8 b, f32x16 c) {
  return __builtin_amdgcn_mfma_f32_32x32x16_bf16(a, b, c, 0, 0, 0);
}

// pack 8 fp32 -> 8 bf16 (RNE via v_cvt_pk_bf16_f32)
__device__ __forceinline__ u16x8 pk8(float4 x, float4 y) {
  u16x8 r;
  ((u32*)&r)[0] = cvtpk(x.x, x.y);
  ((u32*)&r)[1] = cvtpk(x.z, x.w);
  ((u32*)&r)[2] = cvtpk(y.x, y.y);
  ((u32*)&r)[3] = cvtpk(y.z, y.w);
  return r;
}

// ----------------- GEMM: C = A @ B^T + bias, cast fused into staging -------
// A: fp32 [M,K] (AFP32=1) or bf16 [M,K] (AFP32=0); B: fp32 [N,K] weights.
// Reg-staged: global fp32 -> cvt_pk -> ds_write_b128 into [128][32] bf16 LDS.
// OMODE 0: fp32 out. 1: bf16 out (+ncol0). 2: bf16 out scattered vT[b,h,d,s].
template <int OMODE, int AFP32>
__device__ __forceinline__ void gemm_bt_body(const void* __restrict__ Av,
                                             const float* __restrict__ Bw,
                                             const float* __restrict__ bias,
                                             void* __restrict__ Cv, const int K,
                                             const int ldc, const int ncol0,
                                             const int m0, const int n0) {
  __shared__ u16 As[128 * 32];
  __shared__ u16 Bs[128 * 32];
  const int tid = threadIdx.x;
  const int lane = tid & 63;
  const int w = tid >> 6;
  const int l15 = lane & 15;
  const int lg = lane >> 4;

  f32x4 acc[4][4] = {};

  const int arow = (w >> 1) * 64 + l15;
  const int brow = (w & 1) * 64 + l15;
  const int kfb = lg * 16;

  // staging: thread covers rows (srow, srow+64) x 8 k-elements at col sc8
  const int srow = tid >> 2;
  const int sc8 = (tid & 3) * 8;
  const float* Agf = (const float*)Av + (size_t)(m0 + srow) * K + sc8;
  const u16* Agh = (const u16*)Av + (size_t)(m0 + srow) * K + sc8;
  const float* Bgf = Bw + (size_t)(n0 + srow) * K + sc8;
  const size_t rstep = (size_t)64 * K;

  float4 a00, a01, a10, a11, b00, b01, b10, b11;
  u16x8 ah0, ah1;

#define GLOADK(KO)                                                       \
  {                                                                      \
    if (AFP32) {                                                         \
      a00 = *(const float4*)(Agf + (KO));                                \
      a01 = *(const float4*)(Agf + (KO) + 4);                            \
      a10 = *(const float4*)(Agf + (KO) + rstep);                        \
      a11 = *(const float4*)(Agf + (KO) + rstep + 4);                    \
    } else {                                                             \
      ah0 = *(const u16x8*)(Agh + (KO));                                 \
      ah1 = *(const u16x8*)(Agh + (KO) + rstep);                         \
    }                                                                    \
    b00 = *(const float4*)(Bgf + (KO));                                  \
    b01 = *(const float4*)(Bgf + (KO) + 4);                              \
    b10 = *(const float4*)(Bgf + (KO) + rstep);                          \
    b11 = *(const float4*)(Bgf + (KO) + rstep + 4);                      \
  }

  char* const asw = (char*)As + srow * 64 + (tid & 3) * 16;
  char* const bsw = (char*)Bs + srow * 64 + (tid & 3) * 16;

  GLOADK(0);
  for (int k0 = 0; k0 < K; k0 += 32) {
    __syncthreads();  // prior iter's LDS reads done
    if (AFP32) {
      *(u16x8*)asw = pk8(a00, a01);
      *(u16x8*)(asw + 64 * 64) = pk8(a10, a11);
    } else {
      *(u16x8*)asw = ah0;
      *(u16x8*)(asw + 64 * 64) = ah1;
    }
    *(u16x8*)bsw = pk8(b00, b01);
    *(u16x8*)(bsw + 64 * 64) = pk8(b10, b11);
    __syncthreads();  // staged data visible
    if (k0 + 32 < K) GLOADK(k0 + 32);  // prefetch overlaps compute
    bf16x8 af[4], bfv[4];
#pragma unroll
    for (int t = 0; t < 4; ++t) {
      af[t] = ldbf8c((char*)As + (arow + t * 16) * 64 + kfb);
      bfv[t] = ldbf8c((char*)Bs + (brow + t * 16) * 64 + kfb);
    }
    __builtin_amdgcn_s_setprio(1);
#pragma unroll
    for (int i = 0; i < 4; ++i)
#pragma unroll
      for (int j = 0; j < 4; ++j) acc[i][j] = mfma16(af[i], bfv[j], acc[i][j]);
    __builtin_amdgcn_s_setprio(0);
  }
#undef GLOADK

  const int mrow = (w >> 1) * 64 + lg * 4;
  const int ncol = (w & 1) * 64 + l15;
#pragma unroll
  for (int j = 0; j < 4; ++j) {
    const int gn = n0 + ncol + j * 16;
    const float bia = bias[gn];
#pragma unroll
    for (int i = 0; i < 4; ++i) {
      const int gmb = m0 + mrow + i * 16;
#pragma unroll
      for (int r = 0; r < 4; ++r) {
        const float val = acc[i][j][r] + bia;
        const int gm = gmb + r;
        if (OMODE == 0) {
          ((float*)Cv)[(size_t)gm * ldc + gn] = val;
        } else if (OMODE == 1) {
          ((u16*)Cv)[(size_t)gm * ldc + ncol0 + gn] = f2bf(val);
        } else {
          const int bb = gm >> 11, ss = gm & 2047;
          const int hh = gn >> 6, dd = gn & 63;
          ((u16*)Cv)[(((size_t)(bb * 16 + hh) * 64 + dd) << 11) + ss] = f2bf(val);
        }
      }
    }
  }
}

// XCD-chunked QKV projections (768 blocks; xcd = b&7). Reads raw fp32 inputs.
__global__ __launch_bounds__(256, 3) void gemm_qkv_k(
    const float* __restrict__ q, const float* __restrict__ k,
    const float* __restrict__ v, const float* __restrict__ wq,
    const float* __restrict__ wk, const float* __restrict__ wv,
    const float* __restrict__ bq, const float* __restrict__ bk,
    const float* __restrict__ bv, u16* __restrict__ proj, u16* __restrict__ vtb) {
  const int b = blockIdx.x;
  const int xcd = b & 7;
  const int i = b >> 3;
  const int z = i >> 5;
  const int j = i & 31;
  const int m0 = (xcd * 4 + (j >> 3)) * 128;
  const int n0 = (j & 7) * 128;
  if (z == 2)
    gemm_bt_body<2, 1>(v, wv, bv, vtb, DMODEL, 0, 0, m0, n0);
  else
    gemm_bt_body<1, 1>(z == 0 ? q : k, z == 0 ? wq : wk, z == 0 ? bq : bk,
                       proj, DMODEL, LDP, z * DMODEL, m0, n0);
}

__global__ __launch_bounds__(256, 3) void gemm_o_k(const u16* __restrict__ attnb,
                                                   const float* __restrict__ wo,
                                                   const float* __restrict__ bo,
                                                   float* __restrict__ out) {
  const int b = blockIdx.x;
  const int xcd = b & 7;
  const int i = b >> 3;
  const int m0 = (xcd * 4 + (i >> 3)) * 128;
  const int n0 = (i & 7) * 128;
  gemm_bt_body<0, 0>(attnb, wo, bo, out, DMODEL, DMODEL, 0, m0, n0);
}

// ----------------- flash attention: 32x32 MFMA, zero-exchange P -----------
// Round-5 structure (1 barrier/iter, reg prefetch) + V-specific swizzle
// (row&15)<<3 so both V ds_write_b64 and ds_read_b64 phases hit 16 distinct
// bank-pairs (fixes the residual conflict hotspot; K keeps (row&7)<<4 b128).
__global__ __launch_bounds__(256, 2) void attn_k(const u16* __restrict__ proj,
                                                 const u16* __restrict__ vtb,
                                                 u16* __restrict__ outa) {
  __shared__ u16 ks[2][64 * 64];
  __shared__ u16 vs[2][64 * 64];
  const int b = blockIdx.x;
  const int slot = b >> 3;
  const int bh = (b & 7) * 4 + (slot >> 4);
  const int qB = (slot & 15) * 128;
  const int tid = threadIdx.x;
  const int lane = tid & 63;
  const int w = tid >> 6;
  const size_t rb = (size_t)(bh >> 4) * SEQ;
  const int h = bh & 15;
  const int l31 = lane & 31;
  const int hi = lane >> 5;
  const int swzk = (l31 & 7) << 4;
  const int swzv = (l31 & 15) << 3;

  // Q B-frags: Q[q][d = km*16 + hi*8 + j]
  const u16* qp = proj + (rb + qB + w * 32 + l31) * LDP + h * 64 + hi * 8;
  bf16x8 qf[4];
#pragma unroll
  for (int km = 0; km < 4; ++km) qf[km] = ldbf8(qp + km * 16);

  // staging: row = tid>>2 (64 rows), byte col (tid&3)*32
  const int srow = tid >> 2;
  const int scol = (tid & 3) * 32;
  const int scel = scol >> 1;
  const int kz0 = srow * 128 + (scol ^ ((srow & 7) << 4));
  const int kz1 = srow * 128 + ((scol + 16) ^ ((srow & 7) << 4));
  const int vz0 = srow * 128 + (scol ^ ((srow & 15) << 3));
  const int vz1 = srow * 128 + ((scol + 8) ^ ((srow & 15) << 3));
  const int vz2 = srow * 128 + ((scol + 16) ^ ((srow & 15) << 3));
  const int vz3 = srow * 128 + ((scol + 24) ^ ((srow & 15) << 3));
  const u16* kg = proj + rb * LDP + DMODEL + h * 64;  // K rows, stride LDP
  const u16* vg = vtb + (size_t)bh * 64 * SEQ;        // V^T rows [d][s]

  u16x8 ka0, ka1, va0, va1;
  {
    const u16* kr = kg + (size_t)srow * LDP + scel;
    ka0 = *(const u16x8*)kr;
    ka1 = *(const u16x8*)(kr + 8);
    const u16* vr = vg + (size_t)srow * SEQ + scel;
    va0 = *(const u16x8*)vr;
    va1 = *(const u16x8*)(vr + 8);
  }

  f32x16 oa0 = {}, oa1 = {};
  float mrun = -3.0e38f, lrun = 0.f;
  int p = 0;

  for (int kv0 = 0; kv0 < SEQ; kv0 += 64) {
    {
      char* kd = (char*)ks[p];
      char* vd = (char*)vs[p];
      *(u16x8*)(kd + kz0) = ka0;
      *(u16x8*)(kd + kz1) = ka1;
      *(u16x4*)(vd + vz0) = *(u16x4*)&va0;
      *(u16x4*)(vd + vz1) = *((u16x4*)&va0 + 1);
      *(u16x4*)(vd + vz2) = *(u16x4*)&va1;
      *(u16x4*)(vd + vz3) = *((u16x4*)&va1 + 1);
    }
    __syncthreads();  // single barrier per iter
    if (kv0 + 64 < SEQ) {  // prefetch next tile -> regs
      const u16* kr = kg + (size_t)(kv0 + 64 + srow) * LDP + scel;
      ka0 = *(const u16x8*)kr;
      ka1 = *(const u16x8*)(kr + 8);
      const u16* vr = vg + (size_t)srow * SEQ + kv0 + 64 + scel;
      va0 = *(const u16x8*)vr;
      va1 = *(const u16x8*)(vr + 8);
    }
    // ---- QK^T (raw scores) ----
    const char* kp = (const char*)ks[p];
    const char* vp = (const char*)vs[p];
    f32x16 s0 = {}, s1 = {};
    __builtin_amdgcn_s_setprio(1);
#pragma unroll
    for (int km = 0; km < 4; ++km) {
      const int co = (km * 32 + hi * 16) ^ swzk;
      const bf16x8 k0 = ldbf8c(kp + l31 * 128 + co);
      const bf16x8 k1 = ldbf8c(kp + (32 + l31) * 128 + co);
      s0 = mfma32(k0, qf[km], s0);
      s1 = mfma32(k1, qf[km], s1);
    }
    __builtin_amdgcn_s_setprio(0);

    // ---- online softmax (raw-domain max; scale folded into exp fma) ----
    float mxq0 = fmaxf(fmaxf(s0[0], s0[1]), fmaxf(s0[2], s0[3]));
    float mxq1 = fmaxf(fmaxf(s0[4], s0[5]), fmaxf(s0[6], s0[7]));
    float mxq2 = fmaxf(fmaxf(s0[8], s0[9]), fmaxf(s0[10], s0[11]));
    float mxq3 = fmaxf(fmaxf(s0[12], s0[13]), fmaxf(s0[14], s0[15]));
    float mxq4 = fmaxf(fmaxf(s1[0], s1[1]), fmaxf(s1[2], s1[3]));
    float mxq5 = fmaxf(fmaxf(s1[4], s1[5]), fmaxf(s1[6], s1[7]));
    float mxq6 = fmaxf(fmaxf(s1[8], s1[9]), fmaxf(s1[10], s1[11]));
    float mxq7 = fmaxf(fmaxf(s1[12], s1[13]), fmaxf(s1[14], s1[15]));
    float mx = fmaxf(fmaxf(fmaxf(mxq0, mxq1), fmaxf(mxq2, mxq3)),
                     fmaxf(fmaxf(mxq4, mxq5), fmaxf(mxq6, mxq7)));
    mx = fmaxf(mx, __shfl_xor(mx, 32));
    // defer-max: 64.0 raw == 8/ln2 in scaled-log2 domain
    if (!__all(mx <= mrun + 64.0f)) {
      const float mn = fmaxf(mrun, mx);
      const float sf = fexp2((mrun - mn) * SC);
      mrun = mn;
      lrun *= sf;
#pragma unroll
      for (int r = 0; r < 16; ++r) { oa0[r] *= sf; oa1[r] *= sf; }
    }
    const float nmc = -mrun * SC;
#pragma unroll
    for (int r = 0; r < 16; ++r) s0[r] = fexp2(__builtin_fmaf(s0[r], SC, nmc));
#pragma unroll
    for (int r = 0; r < 16; ++r) s1[r] = fexp2(__builtin_fmaf(s1[r], SC, nmc));
    float rs = (((s0[0] + s0[1]) + (s0[2] + s0[3])) +
                ((s0[4] + s0[5]) + (s0[6] + s0[7]))) +
               (((s0[8] + s0[9]) + (s0[10] + s0[11])) +
                ((s0[12] + s0[13]) + (s0[14] + s0[15])));
    rs += (((s1[0] + s1[1]) + (s1[2] + s1[3])) +
           ((s1[4] + s1[5]) + (s1[6] + s1[7]))) +
          (((s1[8] + s1[9]) + (s1[10] + s1[11])) +
           ((s1[12] + s1[13]) + (s1[14] + s1[15])));
    rs += __shfl_xor(rs, 32);
    lrun += rs;

    // ---- PV: 4 chunks of 16 kv; P from own regs only ----
    __builtin_amdgcn_s_setprio(1);
#define PCHUNK(SV, G, CB)                                                \
    {                                                                    \
      u16x8 pbu;                                                         \
      ((u32*)&pbu)[0] = cvtpk(SV[G + 0], SV[G + 1]);                     \
      ((u32*)&pbu)[1] = cvtpk(SV[G + 2], SV[G + 3]);                     \
      ((u32*)&pbu)[2] = cvtpk(SV[G + 4], SV[G + 5]);                     \
      ((u32*)&pbu)[3] = cvtpk(SV[G + 6], SV[G + 7]);                     \
      const bf16x8 pb = __builtin_bit_cast(bf16x8, pbu);                 \
      const int vc0 = ((CB) + 8 * hi) ^ swzv;                            \
      const int vc1 = ((CB) + 16 + 8 * hi) ^ swzv;                       \
      const char* vr0 = vp + l31 * 128;                                  \
      const char* vr1 = vp + (32 + l31) * 128;                           \
      u16x8 vf0, vf1;                                                    \
      *(u16x4*)&vf0       = *(const u16x4*)(vr0 + vc0);                  \
      *((u16x4*)&vf0 + 1) = *(const u16x4*)(vr0 + vc1);                  \
      *(u16x4*)&vf1       = *(const u16x4*)(vr1 + vc0);                  \
      *((u16x4*)&vf1 + 1) = *(const u16x4*)(vr1 + vc1);                  \
      oa0 = mfma32(__builtin_bit_cast(bf16x8, vf0), pb, oa0);            \
      oa1 = mfma32(__builtin_bit_cast(bf16x8, vf1), pb, oa1);            \
    }
    PCHUNK(s0, 0, 0)
    PCHUNK(s0, 8, 32)
    PCHUNK(s1, 0, 64)
    PCHUNK(s1, 8, 96)
#undef PCHUNK
    __builtin_amdgcn_s_setprio(0);
    p ^= 1;
  }

  // ---- epilogue: O^T[d][q] -> attnb[q][h*64+d] ----
  const float invl = 1.0f / lrun;
  u16* orow = outa + (rb + qB + w * 32 + l31) * DMODEL + h * 64 + hi * 4;
#pragma unroll
  for (int g = 0; g < 4; ++g) {
    u16x4 st0, st1;
    ((u32*)&st0)[0] = cvtpk(oa0[4 * g + 0] * invl, oa0[4 * g + 1] * invl);
    ((u32*)&st0)[1] = cvtpk(oa0[4 * g + 2] * invl, oa0[4 * g + 3] * invl);
    *(u16x4*)(orow + 8 * g) = st0;
    ((u32*)&st1)[0] = cvtpk(oa1[4 * g + 0] * invl, oa1[4 * g + 1] * invl);
    ((u32*)&st1)[1] = cvtpk(oa1[4 * g + 2] * invl, oa1[4 * g + 3] * invl);
    *(u16x4*)(orow + 32 + 8 * g) = st1;
  }
}

extern "C" void kernel_launch(void* const* d_in, const int* in_sizes, int n_in,
                              void* d_out, int out_size, void* d_ws, size_t ws_size,
                              hipStream_t stream) {
  const float* q  = (const float*)d_in[0];
  const float* k  = (const float*)d_in[1];
  const float* v  = (const float*)d_in[2];
  const float* wq = (const float*)d_in[3];
  const float* bq = (const float*)d_in[4];
  const float* wk = (const float*)d_in[5];
  const float* bk = (const float*)d_in[6];
  const float* wv = (const float*)d_in[7];
  const float* bv = (const float*)d_in[8];
  const float* wo = (const float*)d_in[9];
  const float* bo = (const float*)d_in[10];

  const size_t NTOK = (size_t)2 * SEQ;
  u16* projb = (u16*)d_ws;               // [4096][3072] bf16 (Q,K sections)
  u16* vtb   = projb + NTOK * LDP;       // [32 bh][64 d][2048 s] bf16
  u16* attnb = vtb + (size_t)32 * 64 * SEQ;  // [4096][1024] bf16

  gemm_qkv_k<<<768, 256, 0, stream>>>(q, k, v, wq, wk, wv, bq, bk, bv, projb,
                                      vtb);
  attn_k<<<512, 256, 0, stream>>>(projb, vtb, attnb);
  gemm_o_k<<<256, 256, 0, stream>>>(attnb, wo, bo, (float*)d_out);
}